// Round 1
// baseline (135.233 us; speedup 1.0000x reference)
//
#include <hip/hip_runtime.h>

// Problem constants (B=4, N=512, D=128, all f32)
#define BB 4
#define NN 512
#define DD 128

static constexpr float LOG2E = 1.4426950408889634f;

#if defined(__has_builtin) && __has_builtin(__builtin_amdgcn_exp2f)
#define EXP2F(x) __builtin_amdgcn_exp2f(x)
#else
#define EXP2F(x) exp2f(x)
#endif

// ---------------------------------------------------------------------------
// Kernel A: input projections.
//   qpT[b*D+e][n] = (q[b,n,:]·Wq[e,:] + bq[e]) * LOG2E   (pre-scaled for exp2)
//   kpT[b*D+e][n] =  k[b,n,:]·Wk[e,:] + bk[e]
//   vpT[b*D+e][n] =  v[b,n,:]·Wv[e,:] + bv[e]
// One block = 4 (b,n) rows, 128 threads (one per output channel e).
// Input-row elements are wave-uniform -> scalar loads; weight rows stream
// per-thread as float4 (L2-resident, 192 KB total).
// ---------------------------------------------------------------------------
__global__ __launch_bounds__(128) void proj_kernel(
    const float* __restrict__ q, const float* __restrict__ k,
    const float* __restrict__ v,
    const float* __restrict__ Wq, const float* __restrict__ bq,
    const float* __restrict__ Wk, const float* __restrict__ bk,
    const float* __restrict__ Wv, const float* __restrict__ bv,
    float* __restrict__ qpT, float* __restrict__ kpT, float* __restrict__ vpT)
{
    const int e  = threadIdx.x;        // output channel 0..127
    const int g0 = blockIdx.x * 4;     // first global row (b*N+n)

    float aq[4] = {0.f, 0.f, 0.f, 0.f};
    float ak[4] = {0.f, 0.f, 0.f, 0.f};
    float av[4] = {0.f, 0.f, 0.f, 0.f};

    const float4* Wq4 = (const float4*)(Wq + e * DD);
    const float4* Wk4 = (const float4*)(Wk + e * DD);
    const float4* Wv4 = (const float4*)(Wv + e * DD);

    #pragma unroll 4
    for (int j4 = 0; j4 < DD / 4; ++j4) {
        const float4 wq = Wq4[j4];
        const float4 wk = Wk4[j4];
        const float4 wv = Wv4[j4];
        #pragma unroll
        for (int r = 0; r < 4; ++r) {
            // wave-uniform addresses -> s_load_dwordx4
            const float4 qr = *(const float4*)(q + (g0 + r) * DD + j4 * 4);
            const float4 kr = *(const float4*)(k + (g0 + r) * DD + j4 * 4);
            const float4 vr = *(const float4*)(v + (g0 + r) * DD + j4 * 4);
            aq[r] = fmaf(qr.x, wq.x, fmaf(qr.y, wq.y, fmaf(qr.z, wq.z, fmaf(qr.w, wq.w, aq[r]))));
            ak[r] = fmaf(kr.x, wk.x, fmaf(kr.y, wk.y, fmaf(kr.z, wk.z, fmaf(kr.w, wk.w, ak[r]))));
            av[r] = fmaf(vr.x, wv.x, fmaf(vr.y, wv.y, fmaf(vr.z, wv.z, fmaf(vr.w, wv.w, av[r]))));
        }
    }

    const float bqe = bq[e], bke = bk[e], bve = bv[e];
    #pragma unroll
    for (int r = 0; r < 4; ++r) {
        const int g = g0 + r;
        const int b = g >> 9;          // g / N
        const int n = g & (NN - 1);    // g % N
        const int base = (b * DD + e) * NN + n;
        qpT[base] = (aq[r] + bqe) * LOG2E;
        kpT[base] = ak[r] + bke;
        vpT[base] = av[r] + bve;
    }
}

// ---------------------------------------------------------------------------
// Kernel C: fused per-channel softmax attention.
// One block per (b,d); thread n owns query n. k/v columns are wave-uniform
// -> scalar (SGPR) loads; inner loop per m: v_mul, v_exp, v_fmac, v_add.
// No max-subtraction needed: |score| <= ~12 in exp2 domain, f32-safe.
// Masked rows (mask==0): all scores equal -> uniform softmax == q=0 path.
// ---------------------------------------------------------------------------
__global__ __launch_bounds__(512) void attn_kernel(
    const float* __restrict__ qpT, const float* __restrict__ kpT,
    const float* __restrict__ vpT, const int* __restrict__ mask,
    float* __restrict__ att)
{
    const int bd = blockIdx.x;         // 0..B*D-1
    const int b  = bd >> 7;            // bd / D
    const int d  = bd & (DD - 1);
    const int n  = threadIdx.x;        // 0..511

    float qv = qpT[bd * NN + n];
    if (mask[b * NN + n] == 0) qv = 0.f;   // uniform softmax == masked semantics

    const float4* kc = (const float4*)(kpT + bd * NN);
    const float4* vc = (const float4*)(vpT + bd * NN);

    float num = 0.f, den = 0.f;
    #pragma unroll 4
    for (int m4 = 0; m4 < NN / 4; ++m4) {
        const float4 k4 = kc[m4];      // wave-uniform -> s_load_dwordx4
        const float4 v4 = vc[m4];
        const float p0 = EXP2F(qv * k4.x);
        const float p1 = EXP2F(qv * k4.y);
        const float p2 = EXP2F(qv * k4.z);
        const float p3 = EXP2F(qv * k4.w);
        num = fmaf(p0, v4.x, num);
        num = fmaf(p1, v4.y, num);
        num = fmaf(p2, v4.z, num);
        num = fmaf(p3, v4.w, num);
        den += (p0 + p1) + (p2 + p3);
    }

    att[(b * NN + n) * DD + d] = num / den;
}

// ---------------------------------------------------------------------------
// Kernel D: output projection. out[b,n,e] = att[b,n,:]·Wo[e,:] + bo[e]
// Same structure as kernel A (att rows via scalar loads, Wo streamed float4).
// ---------------------------------------------------------------------------
__global__ __launch_bounds__(128) void outproj_kernel(
    const float* __restrict__ att, const float* __restrict__ Wo,
    const float* __restrict__ bo, float* __restrict__ out)
{
    const int e  = threadIdx.x;
    const int g0 = blockIdx.x * 4;

    float acc[4];
    const float boe = bo[e];
    #pragma unroll
    for (int r = 0; r < 4; ++r) acc[r] = boe;

    const float4* Wo4 = (const float4*)(Wo + e * DD);

    #pragma unroll 4
    for (int j4 = 0; j4 < DD / 4; ++j4) {
        const float4 w = Wo4[j4];
        #pragma unroll
        for (int r = 0; r < 4; ++r) {
            const float4 a = *(const float4*)(att + (g0 + r) * DD + j4 * 4);
            acc[r] = fmaf(a.x, w.x, fmaf(a.y, w.y, fmaf(a.z, w.z, fmaf(a.w, w.w, acc[r]))));
        }
    }

    #pragma unroll
    for (int r = 0; r < 4; ++r)
        out[(g0 + r) * DD + e] = acc[r];
}

// ---------------------------------------------------------------------------
extern "C" void kernel_launch(void* const* d_in, const int* in_sizes, int n_in,
                              void* d_out, int out_size, void* d_ws, size_t ws_size,
                              hipStream_t stream)
{
    const float* q    = (const float*)d_in[0];
    const float* k    = (const float*)d_in[1];
    const float* v    = (const float*)d_in[2];
    const int*   mask = (const int*)  d_in[3];
    const float* Wq   = (const float*)d_in[4];
    const float* bq   = (const float*)d_in[5];
    const float* Wk   = (const float*)d_in[6];
    const float* bk   = (const float*)d_in[7];
    const float* Wv   = (const float*)d_in[8];
    const float* bv   = (const float*)d_in[9];
    const float* Wo   = (const float*)d_in[10];
    const float* bo   = (const float*)d_in[11];
    float* out = (float*)d_out;

    // workspace: 4 arrays of B*D*N f32 = 4 MB total
    float* ws  = (float*)d_ws;
    float* qpT = ws;                       // [B*D][N], pre-scaled by log2(e)
    float* kpT = ws + 1 * BB * DD * NN;    // [B*D][N]
    float* vpT = ws + 2 * BB * DD * NN;    // [B*D][N]
    float* att = ws + 3 * BB * DD * NN;    // [B*N][D] row-major

    proj_kernel<<<BB * NN / 4, 128, 0, stream>>>(q, k, v, Wq, bq, Wk, bk, Wv, bv,
                                                 qpT, kpT, vpT);
    attn_kernel<<<BB * DD, 512, 0, stream>>>(qpT, kpT, vpT, mask, att);
    outproj_kernel<<<BB * NN / 4, 128, 0, stream>>>(att, Wo, bo, out);
}

// Round 2
// 133.609 us; speedup vs baseline: 1.0122x; 1.0122x over previous
//
#include <hip/hip_runtime.h>

// Problem constants (B=4, N=512, D=128, all f32)
#define BB 4
#define NN 512
#define DD 128
#define RR 8   // rows per projection block

static constexpr float LOG2E = 1.4426950408889634f;
#define EXP2F(x) __builtin_amdgcn_exp2f(x)

// ---------------------------------------------------------------------------
// Kernel T: transpose all 4 weight matrices into ws.
//   WT[m][j][e] = W_m[e][j],  m = 0:q 1:k 2:v 3:o
// Read coalesced over j (lane dim); scattered 4B writes are L2-absorbed
// (total 256 KB).
// ---------------------------------------------------------------------------
__global__ __launch_bounds__(256) void wtrans_kernel(
    const float* __restrict__ Wq, const float* __restrict__ Wk,
    const float* __restrict__ Wv, const float* __restrict__ Wo,
    float* __restrict__ WT)
{
    const int l = blockIdx.x * 256 + threadIdx.x;   // 0..65535
    const int m = l >> 14;
    const int e = (l >> 7) & (DD - 1);
    const int j = l & (DD - 1);
    const float* W = (m == 0) ? Wq : (m == 1) ? Wk : (m == 2) ? Wv : Wo;
    WT[(m << 14) + j * DD + e] = W[e * DD + j];
}

// ---------------------------------------------------------------------------
// Kernel A: input projections using transposed weights.
// grid = (2048/RR, 3); block = 128 (lane = output channel e).
// Weight loads WT[j][e] are lane-coalesced (256 B/instr); input rows are
// wave-uniform -> s_load_dwordx4 (stay off the VALU/VMEM-lane path).
//   qpT[b*D+e][n] = (q[b,n,:]·Wq[e,:] + bq[e]) * LOG2E   (pre-scaled for exp2)
//   kpT/vpT analogous (scale 1).
// ---------------------------------------------------------------------------
__global__ __launch_bounds__(128) void proj_kernel(
    const float* __restrict__ q, const float* __restrict__ k,
    const float* __restrict__ v, const float* __restrict__ WT,
    const float* __restrict__ bq, const float* __restrict__ bk,
    const float* __restrict__ bv,
    float* __restrict__ qpT, float* __restrict__ kpT, float* __restrict__ vpT)
{
    const int e  = threadIdx.x;          // output channel, lane dim
    const int t  = blockIdx.y;           // 0=q, 1=k, 2=v
    const int g0 = blockIdx.x * RR;      // first global row (b*N+n)

    const float* x    = (t == 0) ? q   : (t == 1) ? k   : v;
    const float* wt   = WT + (t << 14);
    const float* bias = (t == 0) ? bq  : (t == 1) ? bk  : bv;
    float*       outp = (t == 0) ? qpT : (t == 1) ? kpT : vpT;
    const float scale = (t == 0) ? LOG2E : 1.0f;

    float acc[RR];
    #pragma unroll
    for (int r = 0; r < RR; ++r) acc[r] = 0.f;

    #pragma unroll 4
    for (int j4 = 0; j4 < DD / 4; ++j4) {
        const float w0 = wt[(j4 * 4 + 0) * DD + e];   // coalesced
        const float w1 = wt[(j4 * 4 + 1) * DD + e];
        const float w2 = wt[(j4 * 4 + 2) * DD + e];
        const float w3 = wt[(j4 * 4 + 3) * DD + e];
        #pragma unroll
        for (int r = 0; r < RR; ++r) {
            const float4 xr = *(const float4*)(x + (g0 + r) * DD + j4 * 4); // uniform -> s_load
            acc[r] = fmaf(xr.x, w0, fmaf(xr.y, w1, fmaf(xr.z, w2, fmaf(xr.w, w3, acc[r]))));
        }
    }

    const float be = bias[e];
    #pragma unroll
    for (int r = 0; r < RR; ++r) {
        const int g = g0 + r;
        const int b = g >> 9;            // g / N
        const int n = g & (NN - 1);      // g % N
        outp[(b * DD + e) * NN + n] = (acc[r] + be) * scale;
    }
}

// ---------------------------------------------------------------------------
// Kernel C: fused per-channel softmax attention.
// One block per (b,d); thread n owns query n. k/v columns are wave-uniform
// -> s_load_dwordx4; unroll 8 keeps 16 scalar loads in flight. Accumulators
// split 4+2 ways to break the serial fmaf chains.
// No max-subtraction: |score| <= ~17 in exp2 domain, sums < 1e8 — f32-safe.
// Masked rows (mask==0): all scores equal -> uniform softmax == qv=0 path.
// ---------------------------------------------------------------------------
__global__ __launch_bounds__(512) void attn_kernel(
    const float* __restrict__ qpT, const float* __restrict__ kpT,
    const float* __restrict__ vpT, const int* __restrict__ mask,
    float* __restrict__ att)
{
    const int bd = blockIdx.x;           // 0..B*D-1
    const int b  = bd >> 7;              // bd / D
    const int d  = bd & (DD - 1);
    const int n  = threadIdx.x;          // 0..511

    float qv = qpT[bd * NN + n];
    if (mask[b * NN + n] == 0) qv = 0.f;

    const float4* kc = (const float4*)(kpT + bd * NN);
    const float4* vc = (const float4*)(vpT + bd * NN);

    float n0 = 0.f, n1 = 0.f, n2 = 0.f, n3 = 0.f;
    float d0 = 0.f, d1 = 0.f;
    #pragma unroll 8
    for (int m4 = 0; m4 < NN / 4; ++m4) {
        const float4 k4 = kc[m4];        // wave-uniform -> s_load_dwordx4
        const float4 v4 = vc[m4];
        const float p0 = EXP2F(qv * k4.x);
        const float p1 = EXP2F(qv * k4.y);
        const float p2 = EXP2F(qv * k4.z);
        const float p3 = EXP2F(qv * k4.w);
        n0 = fmaf(p0, v4.x, n0);
        n1 = fmaf(p1, v4.y, n1);
        n2 = fmaf(p2, v4.z, n2);
        n3 = fmaf(p3, v4.w, n3);
        d0 += p0 + p1;
        d1 += p2 + p3;
    }

    att[(b * NN + n) * DD + d] = ((n0 + n1) + (n2 + n3)) / (d0 + d1);
}

// ---------------------------------------------------------------------------
// Kernel D: output projection, same structure as proj_kernel.
//   out[b,n,e] = att[b,n,:]·Wo[e,:] + bo[e]
// Output writes are lane-coalesced.
// ---------------------------------------------------------------------------
__global__ __launch_bounds__(128) void outproj_kernel(
    const float* __restrict__ att, const float* __restrict__ WT,
    const float* __restrict__ bo, float* __restrict__ out)
{
    const int e  = threadIdx.x;
    const int g0 = blockIdx.x * RR;
    const float* wt = WT + (3 << 14);    // Wo^T slot

    float acc[RR];
    #pragma unroll
    for (int r = 0; r < RR; ++r) acc[r] = 0.f;

    #pragma unroll 4
    for (int j4 = 0; j4 < DD / 4; ++j4) {
        const float w0 = wt[(j4 * 4 + 0) * DD + e];
        const float w1 = wt[(j4 * 4 + 1) * DD + e];
        const float w2 = wt[(j4 * 4 + 2) * DD + e];
        const float w3 = wt[(j4 * 4 + 3) * DD + e];
        #pragma unroll
        for (int r = 0; r < RR; ++r) {
            const float4 a = *(const float4*)(att + (g0 + r) * DD + j4 * 4); // uniform -> s_load
            acc[r] = fmaf(a.x, w0, fmaf(a.y, w1, fmaf(a.z, w2, fmaf(a.w, w3, acc[r]))));
        }
    }

    const float boe = bo[e];
    #pragma unroll
    for (int r = 0; r < RR; ++r)
        out[(g0 + r) * DD + e] = acc[r] + boe;   // coalesced
}

// ---------------------------------------------------------------------------
extern "C" void kernel_launch(void* const* d_in, const int* in_sizes, int n_in,
                              void* d_out, int out_size, void* d_ws, size_t ws_size,
                              hipStream_t stream)
{
    const float* q    = (const float*)d_in[0];
    const float* k    = (const float*)d_in[1];
    const float* v    = (const float*)d_in[2];
    const int*   mask = (const int*)  d_in[3];
    const float* Wq   = (const float*)d_in[4];
    const float* bq   = (const float*)d_in[5];
    const float* Wk   = (const float*)d_in[6];
    const float* bk   = (const float*)d_in[7];
    const float* Wv   = (const float*)d_in[8];
    const float* bv   = (const float*)d_in[9];
    const float* Wo   = (const float*)d_in[10];
    const float* bo   = (const float*)d_in[11];
    float* out = (float*)d_out;

    // ws layout (floats): qpT | kpT | vpT | att | WT[4]
    float* ws  = (float*)d_ws;
    float* qpT = ws;                           // [B*D][N], pre-scaled by log2(e)
    float* kpT = ws + 1 * BB * DD * NN;        // [B*D][N]
    float* vpT = ws + 2 * BB * DD * NN;        // [B*D][N]
    float* att = ws + 3 * BB * DD * NN;        // [B*N][D]
    float* WT  = ws + 4 * BB * DD * NN;        // [4][128][128] transposed weights

    wtrans_kernel<<<4 * DD * DD / 256, 256, 0, stream>>>(Wq, Wk, Wv, Wo, WT);

    dim3 pgrid(BB * NN / RR, 3);
    proj_kernel<<<pgrid, 128, 0, stream>>>(q, k, v, WT, bq, bk, bv, qpT, kpT, vpT);

    attn_kernel<<<BB * DD, 512, 0, stream>>>(qpT, kpT, vpT, mask, att);

    outproj_kernel<<<BB * NN / RR, 128, 0, stream>>>(att, WT, bo, out);
}

// Round 3
// 130.736 us; speedup vs baseline: 1.0344x; 1.0220x over previous
//
#include <hip/hip_runtime.h>

// Problem constants (B=4, N=512, D=128, all f32)
#define BB 4
#define NN 512
#define DD 128

static constexpr float LOG2E = 1.4426950408889634f;
#define EXP2F(x) __builtin_amdgcn_exp2f(x)

// ---------------------------------------------------------------------------
// Kernel T: repack all 4 weight matrices into ws.
//   WTp[t][j4][e][c] = W_t[e][j4*4+c]   (t = 0:q 1:k 2:v 3:o, c = 0..3)
// so a proj thread (lane = e) loads one coalesced float4 of 4 consecutive
// j's for its channel e. Reads coalesced over j; writes scattered 16B
// (256 KB total, L2-absorbed).
// ---------------------------------------------------------------------------
__global__ __launch_bounds__(256) void wtrans_kernel(
    const float* __restrict__ Wq, const float* __restrict__ Wk,
    const float* __restrict__ Wv, const float* __restrict__ Wo,
    float* __restrict__ WTp)
{
    const int l = blockIdx.x * 256 + threadIdx.x;   // 0..65535
    const int t = l >> 14;
    const int e = (l >> 7) & (DD - 1);
    const int j = l & (DD - 1);
    const float* W = (t == 0) ? Wq : (t == 1) ? Wk : (t == 2) ? Wv : Wo;
    WTp[(t << 14) + (j >> 2) * (DD * 4) + e * 4 + (j & 3)] = W[e * DD + j];
}

// ---------------------------------------------------------------------------
// Kernel A: input projections.
// grid = (2048/8, 3); block = 512: lane = channel e, wave-pair sub = tid>>7
// owns 2 rows. 6144 waves total = 6 waves/SIMD (latency hiding — R1/R2 ran
// at 1.5/SIMD and sat at 9% VALUBusy).
// Weight: one coalesced global_load_dwordx4 per j4 (WTp layout).
// Input rows: wave-uniform -> s_load_dwordx4.
//   qpT[b*D+e][n] = (q[b,n,:]·Wq[e,:] + bq[e]) * LOG2E   (pre-scaled for exp2)
// ---------------------------------------------------------------------------
__global__ __launch_bounds__(512) void proj_kernel(
    const float* __restrict__ q, const float* __restrict__ k,
    const float* __restrict__ v, const float* __restrict__ WTp,
    const float* __restrict__ bq, const float* __restrict__ bk,
    const float* __restrict__ bv,
    float* __restrict__ qpT, float* __restrict__ kpT, float* __restrict__ vpT)
{
    const int t   = blockIdx.y;                  // 0=q, 1=k, 2=v
    const int e   = threadIdx.x & (DD - 1);      // output channel, lane dim
    const int sub = threadIdx.x >> 7;            // wave-uniform within a wave
    const int g0  = blockIdx.x * 8 + sub * 2;    // rows g0, g0+1

    const float*  x    = (t == 0) ? q   : (t == 1) ? k   : v;
    const float4* wt4  = (const float4*)(WTp + (t << 14));
    const float*  bias = (t == 0) ? bq  : (t == 1) ? bk  : bv;
    float*        outp = (t == 0) ? qpT : (t == 1) ? kpT : vpT;
    const float scale  = (t == 0) ? LOG2E : 1.0f;

    const float4* x0 = (const float4*)(x + g0 * DD);
    const float4* x1 = (const float4*)(x + (g0 + 1) * DD);

    float a0 = 0.f, a1 = 0.f;
    #pragma unroll 8
    for (int j4 = 0; j4 < DD / 4; ++j4) {
        const float4 w  = wt4[j4 * DD + e];      // coalesced dwordx4
        const float4 r0 = x0[j4];                // uniform -> s_load_dwordx4
        const float4 r1 = x1[j4];
        a0 = fmaf(r0.x, w.x, fmaf(r0.y, w.y, fmaf(r0.z, w.z, fmaf(r0.w, w.w, a0))));
        a1 = fmaf(r1.x, w.x, fmaf(r1.y, w.y, fmaf(r1.z, w.z, fmaf(r1.w, w.w, a1))));
    }

    const float be = bias[e];
    {
        const int b = g0 >> 9, n = g0 & (NN - 1);
        outp[(b * DD + e) * NN + n] = (a0 + be) * scale;
    }
    {
        const int g = g0 + 1;
        const int b = g >> 9, n = g & (NN - 1);
        outp[(b * DD + e) * NN + n] = (a1 + be) * scale;
    }
}

// ---------------------------------------------------------------------------
// Kernel C: fused per-channel softmax attention.
// One block per (b,d); thread n owns query n. k/v columns staged once in
// LDS (coalesced), inner loop reads ds_read_b128 broadcast (same address
// across lanes = conflict-free) — replaces R2's SMEM latency chains.
// No max-subtraction: |score| <= ~17 in exp2 domain, sums < 1e8 — f32-safe.
// Masked rows (mask==0): all scores equal -> uniform softmax == qv=0 path.
// ---------------------------------------------------------------------------
__global__ __launch_bounds__(512) void attn_kernel(
    const float* __restrict__ qpT, const float* __restrict__ kpT,
    const float* __restrict__ vpT, const int* __restrict__ mask,
    float* __restrict__ att)
{
    __shared__ float sk[NN];
    __shared__ float sv[NN];

    const int bd = blockIdx.x;           // 0..B*D-1
    const int b  = bd >> 7;              // bd / D
    const int d  = bd & (DD - 1);
    const int n  = threadIdx.x;          // 0..511

    sk[n] = kpT[bd * NN + n];            // coalesced
    sv[n] = vpT[bd * NN + n];

    float qv = qpT[bd * NN + n];
    if (mask[b * NN + n] == 0) qv = 0.f;
    __syncthreads();

    const float4* k4p = (const float4*)sk;
    const float4* v4p = (const float4*)sv;

    float n0 = 0.f, n1 = 0.f, n2 = 0.f, n3 = 0.f;
    float d0 = 0.f, d1 = 0.f;
    #pragma unroll 8
    for (int m4 = 0; m4 < NN / 4; ++m4) {
        const float4 k4 = k4p[m4];       // ds_read_b128 broadcast
        const float4 v4 = v4p[m4];
        const float p0 = EXP2F(qv * k4.x);
        const float p1 = EXP2F(qv * k4.y);
        const float p2 = EXP2F(qv * k4.z);
        const float p3 = EXP2F(qv * k4.w);
        n0 = fmaf(p0, v4.x, n0);
        n1 = fmaf(p1, v4.y, n1);
        n2 = fmaf(p2, v4.z, n2);
        n3 = fmaf(p3, v4.w, n3);
        d0 += p0 + p1;
        d1 += p2 + p3;
    }

    att[(b * NN + n) * DD + d] = ((n0 + n1) + (n2 + n3)) / (d0 + d1);
}

// ---------------------------------------------------------------------------
// Kernel D: output projection. out[b,n,e] = att[b,n,:]·Wo[e,:] + bo[e]
// block = 512: lane = e, sub = tid>>7 owns 1 row. grid 512 -> 4096 waves
// = 4 waves/SIMD. Weight float4 coalesced; att rows uniform s_load.
// ---------------------------------------------------------------------------
__global__ __launch_bounds__(512) void outproj_kernel(
    const float* __restrict__ att, const float* __restrict__ WTp,
    const float* __restrict__ bo, float* __restrict__ out)
{
    const int e   = threadIdx.x & (DD - 1);
    const int sub = threadIdx.x >> 7;
    const int g   = blockIdx.x * 4 + sub;

    const float4* wt4 = (const float4*)(WTp + (3 << 14));   // Wo slot
    const float4* xr  = (const float4*)(att + g * DD);

    float acc = 0.f;
    #pragma unroll 8
    for (int j4 = 0; j4 < DD / 4; ++j4) {
        const float4 w = wt4[j4 * DD + e];   // coalesced dwordx4
        const float4 a = xr[j4];             // uniform -> s_load_dwordx4
        acc = fmaf(a.x, w.x, fmaf(a.y, w.y, fmaf(a.z, w.z, fmaf(a.w, w.w, acc))));
    }

    out[g * DD + e] = acc + bo[e];           // coalesced
}

// ---------------------------------------------------------------------------
extern "C" void kernel_launch(void* const* d_in, const int* in_sizes, int n_in,
                              void* d_out, int out_size, void* d_ws, size_t ws_size,
                              hipStream_t stream)
{
    const float* q    = (const float*)d_in[0];
    const float* k    = (const float*)d_in[1];
    const float* v    = (const float*)d_in[2];
    const int*   mask = (const int*)  d_in[3];
    const float* Wq   = (const float*)d_in[4];
    const float* bq   = (const float*)d_in[5];
    const float* Wk   = (const float*)d_in[6];
    const float* bk   = (const float*)d_in[7];
    const float* Wv   = (const float*)d_in[8];
    const float* bv   = (const float*)d_in[9];
    const float* Wo   = (const float*)d_in[10];
    const float* bo   = (const float*)d_in[11];
    float* out = (float*)d_out;

    // ws layout (floats): qpT | kpT | vpT | att | WTp[4]  (~4.25 MB)
    float* ws  = (float*)d_ws;
    float* qpT = ws;                           // [B*D][N], pre-scaled by log2(e)
    float* kpT = ws + 1 * BB * DD * NN;        // [B*D][N]
    float* vpT = ws + 2 * BB * DD * NN;        // [B*D][N]
    float* att = ws + 3 * BB * DD * NN;        // [B*N][D]
    float* WTp = ws + 4 * BB * DD * NN;        // [4][32][128][4] repacked weights

    wtrans_kernel<<<4 * DD * DD / 256, 256, 0, stream>>>(Wq, Wk, Wv, Wo, WTp);

    dim3 pgrid(BB * NN / 8, 3);
    proj_kernel<<<pgrid, 512, 0, stream>>>(q, k, v, WTp, bq, bk, bv, qpT, kpT, vpT);

    attn_kernel<<<BB * DD, 512, 0, stream>>>(qpT, kpT, vpT, mask, att);

    outproj_kernel<<<BB * NN / 4, 512, 0, stream>>>(att, WTp, bo, out);
}